// Round 1
// baseline (158.280 us; speedup 1.0000x reference)
//
#include <hip/hip_runtime.h>
#include <math.h>

#define VOCAB 50000
#define D_WORD 300
#define D_TOPIC 128
#define DH 312            // D_NOUN_HIDDEN
#define NB 8192
#define LMAX 32
#define N_MONTH 12

// ---------------------------------------------------------------------------
// Kernel 1 (tiny): w = k_w^T @ (q_w @ topic_emb + q_b).  One block.
// Bias k_b and month term cancel in softmax, so only w[0:300] matters for
// scores; we still compute all 312 (harmless).
// ---------------------------------------------------------------------------
__global__ __launch_bounds__(320) void compute_w_kernel(
    const float* __restrict__ topic_emb,
    const float* __restrict__ q_w, const float* __restrict__ q_b,
    const float* __restrict__ k_w,
    float* __restrict__ w_out)
{
    __shared__ float query_s[D_TOPIC];
    int t = threadIdx.x;
    if (t < D_TOPIC) {
        float q = q_b[t];
        for (int k = 0; k < D_TOPIC; ++k)
            q = fmaf(q_w[t * D_TOPIC + k], topic_emb[k], q);
        query_s[t] = q;
    }
    __syncthreads();
    if (t < DH) {
        float acc = 0.f;
        for (int d = 0; d < D_TOPIC; ++d)
            acc = fmaf(k_w[d * DH + t], query_s[d], acc);   // coalesced over t
        w_out[t] = acc;
    }
}

// ---------------------------------------------------------------------------
// Kernel 2: s_vocab[v] = we[v, 0:300] . w[0:300].  One wave per row,
// coalesced 64-lane strided loads, shuffle reduce.
// ---------------------------------------------------------------------------
__global__ __launch_bounds__(256) void vocab_score_kernel(
    const float* __restrict__ we, const float* __restrict__ w,
    float* __restrict__ s_vocab)
{
    __shared__ float w_s[D_WORD];
    int t = threadIdx.x;
    for (int j = t; j < D_WORD; j += 256) w_s[j] = w[j];
    __syncthreads();
    int wave = t >> 6, lane = t & 63;
    int row = blockIdx.x * 4 + wave;
    if (row >= VOCAB) return;
    const float* r = we + (size_t)row * D_WORD;
    float p = 0.f;
    for (int c = lane; c < D_WORD; c += 64)
        p = fmaf(r[c], w_s[c], p);
    #pragma unroll
    for (int off = 32; off > 0; off >>= 1)
        p += __shfl_xor(p, off);
    if (lane == 0) s_vocab[row] = p;
}

// ---------------------------------------------------------------------------
// Kernel 3: per-sample softmax over gathered s_vocab + weighted row sum.
// One block (320 thr = 5 waves) per sample.  Wave 0: gather ids/scores,
// 64-lane shuffle softmax.  Then thread j<300 accumulates output column j
// (row reads coalesced, attn broadcast from LDS); threads 300..311 write
// the one-hot month part (softmax sums to 1 exactly in the reference algebra).
// ---------------------------------------------------------------------------
__global__ __launch_bounds__(320) void attn_kernel(
    const int* __restrict__ noun_ids, const int* __restrict__ lengths,
    const int* __restrict__ months, const int* __restrict__ encode_p,
    const float* __restrict__ we, const float* __restrict__ s_vocab,
    float* __restrict__ out)
{
    int b = blockIdx.x;
    int t = threadIdx.x;
    float* ob = out + (size_t)b * DH;
    int len = lengths[b];
    if (len <= 0) {                       // reference leaves empty samples zero
        if (t < DH) ob[t] = 0.f;          // d_out is poisoned -> must write
        return;
    }
    if (len > LMAX) len = LMAX;

    __shared__ float attn_s[LMAX];
    __shared__ int ids_s[LMAX];

    if (t < 64) {                         // exactly wave 0
        float sc = -INFINITY;
        if (t < LMAX) {
            int id = noun_ids[b * LMAX + t];
            ids_s[t] = id;
            if (t < len) sc = s_vocab[id] * 0.08838834764831845f; // 1/sqrt(128)
        }
        float m = sc;
        #pragma unroll
        for (int off = 32; off > 0; off >>= 1) m = fmaxf(m, __shfl_xor(m, off));
        float e = (t < len && t < LMAX) ? __expf(sc - m) : 0.f;
        float s = e;
        #pragma unroll
        for (int off = 32; off > 0; off >>= 1) s += __shfl_xor(s, off);
        if (t < LMAX) attn_s[t] = e / s;
    }
    __syncthreads();

    if (t < D_WORD) {
        float acc = 0.f;
        for (int l = 0; l < len; ++l)
            acc = fmaf(attn_s[l], we[(size_t)ids_s[l] * D_WORD + t], acc);
        ob[t] = acc;
    } else if (t < DH) {
        int m = t - D_WORD;
        ob[t] = (m == months[b]) ? (float)(*encode_p) : 0.f;
    }
}

// ---------------------------------------------------------------------------
extern "C" void kernel_launch(void* const* d_in, const int* in_sizes, int n_in,
                              void* d_out, int out_size, void* d_ws, size_t ws_size,
                              hipStream_t stream) {
    const float* topic_emb = (const float*)d_in[0];
    const int*   noun_ids  = (const int*)d_in[1];
    const int*   lengths   = (const int*)d_in[2];
    const int*   months    = (const int*)d_in[3];
    const int*   encode    = (const int*)d_in[4];
    const float* we        = (const float*)d_in[5];
    const float* k_w       = (const float*)d_in[6];
    // d_in[7] = k_b: bias cancels in softmax; its output contribution is
    // already folded out (key bias doesn't touch `value`), so unused.
    const float* q_w       = (const float*)d_in[8];
    const float* q_b       = (const float*)d_in[9];
    float* out = (float*)d_out;

    float* w_vec   = (float*)d_ws;       // 312 floats (padded to 512)
    float* s_vocab = w_vec + 512;        // 50000 floats  (~202 KB total ws)

    compute_w_kernel<<<1, 320, 0, stream>>>(topic_emb, q_w, q_b, k_w, w_vec);
    vocab_score_kernel<<<(VOCAB + 3) / 4, 256, 0, stream>>>(we, w_vec, s_vocab);
    attn_kernel<<<NB, 320, 0, stream>>>(noun_ids, lengths, months, encode,
                                        we, s_vocab, out);
}

// Round 2
// 148.508 us; speedup vs baseline: 1.0658x; 1.0658x over previous
//
#include <hip/hip_runtime.h>
#include <math.h>

#define VOCAB 50000
#define D_WORD 300
#define D_TOPIC 128
#define DH 312            // D_NOUN_HIDDEN
#define NB 8192
#define LMAX 32
#define N_MONTH 12

// ---------------------------------------------------------------------------
// Kernel 1 (tiny): w = k_w^T @ (q_w @ topic_emb + q_b).  One block.
// k_b and the month one-hot cancel in the softmax, so only w[0:300] feeds
// scores; computing all 312 is harmless.
// ---------------------------------------------------------------------------
__global__ __launch_bounds__(320) void compute_w_kernel(
    const float* __restrict__ topic_emb,
    const float* __restrict__ q_w, const float* __restrict__ q_b,
    const float* __restrict__ k_w,
    float* __restrict__ w_out)
{
    __shared__ float query_s[D_TOPIC];
    int t = threadIdx.x;
    if (t < D_TOPIC) {
        float q = q_b[t];
        for (int k = 0; k < D_TOPIC; ++k)
            q = fmaf(q_w[t * D_TOPIC + k], topic_emb[k], q);
        query_s[t] = q;
    }
    __syncthreads();
    if (t < DH) {
        float acc = 0.f;
        for (int d = 0; d < D_TOPIC; ++d)
            acc = fmaf(k_w[d * DH + t], query_s[d], acc);   // coalesced over t
        w_out[t] = acc;
    }
}

// ---------------------------------------------------------------------------
// Kernel 2: s_vocab[v] = we[v, 0:300] . w[0:300].  One wave per row,
// float4 loads (row pitch 1200 B = 75 x 16 B, 16B-aligned), shuffle reduce.
// ---------------------------------------------------------------------------
__global__ __launch_bounds__(256) void vocab_score_kernel(
    const float* __restrict__ we, const float* __restrict__ w,
    float* __restrict__ s_vocab)
{
    __shared__ float4 w4[75];
    int t = threadIdx.x;
    if (t < 75) w4[t] = ((const float4*)w)[t];
    __syncthreads();
    int wave = t >> 6, lane = t & 63;
    int row = blockIdx.x * 4 + wave;
    if (row >= VOCAB) return;
    const float4* r = (const float4*)(we + (size_t)row * D_WORD);
    float4 a = r[lane];
    float4 ww = w4[lane];
    float p = fmaf(a.x, ww.x, fmaf(a.y, ww.y, fmaf(a.z, ww.z, a.w * ww.w)));
    if (lane < 11) {
        float4 b = r[64 + lane];
        float4 wb = w4[64 + lane];
        p = fmaf(b.x, wb.x, fmaf(b.y, wb.y, fmaf(b.z, wb.z, fmaf(b.w, wb.w, p))));
    }
    #pragma unroll
    for (int off = 32; off > 0; off >>= 1)
        p += __shfl_xor(p, off);
    if (lane == 0) s_vocab[row] = p;
}

// ---------------------------------------------------------------------------
// Kernel 3: one WAVE per sample, no LDS, no barriers.  Lanes 0..31 gather
// s_vocab[id]; width-64 shuffle softmax (inactive lanes contribute -inf/0);
// weighted row sum with float4 loads: lane covers cols [4L,4L+4), lanes<11
// also cols [256+4L, ...).  Month one-hot written by lanes 11..13
// (softmax sums to 1, so the month part of `out` is exactly the one-hot).
// ---------------------------------------------------------------------------
__global__ __launch_bounds__(256) void attn_kernel(
    const int* __restrict__ noun_ids, const int* __restrict__ lengths,
    const int* __restrict__ months, const int* __restrict__ encode_p,
    const float* __restrict__ we, const float* __restrict__ s_vocab,
    float* __restrict__ out)
{
    int wave = threadIdx.x >> 6, lane = threadIdx.x & 63;
    int b = blockIdx.x * 4 + wave;
    float4* ob = (float4*)(out + (size_t)b * DH);   // 78 float4 per row
    int len = lengths[b];

    if (len <= 0) {                   // reference leaves empty samples zero;
        float4 z = {0.f, 0.f, 0.f, 0.f};   // d_out is poisoned -> must write
        ob[lane] = z;
        if (lane < 14) ob[64 + lane] = z;
        return;                       // len uniform per wave: no divergence
    }
    if (len > LMAX) len = LMAX;

    int id = 0;
    float sc = -INFINITY;
    if (lane < LMAX) {
        id = noun_ids[b * LMAX + lane];
        if (lane < len) sc = s_vocab[id] * 0.08838834764831845f; // 1/sqrt(128)
    }
    float m = sc;
    #pragma unroll
    for (int off = 32; off > 0; off >>= 1) m = fmaxf(m, __shfl_xor(m, off));
    float e = (lane < len) ? __expf(sc - m) : 0.f;
    float s = e;
    #pragma unroll
    for (int off = 32; off > 0; off >>= 1) s += __shfl_xor(s, off);
    float rs = 1.f / s;

    float4 acc0 = {0.f, 0.f, 0.f, 0.f};
    float4 acc1 = {0.f, 0.f, 0.f, 0.f};
    for (int l = 0; l < len; ++l) {
        float a = __shfl(e, l) * rs;
        int rid = __shfl(id, l);
        const float4* r = (const float4*)(we + (size_t)rid * D_WORD);
        float4 v = r[lane];
        acc0.x = fmaf(a, v.x, acc0.x);
        acc0.y = fmaf(a, v.y, acc0.y);
        acc0.z = fmaf(a, v.z, acc0.z);
        acc0.w = fmaf(a, v.w, acc0.w);
        if (lane < 11) {
            float4 v1 = r[64 + lane];
            acc1.x = fmaf(a, v1.x, acc1.x);
            acc1.y = fmaf(a, v1.y, acc1.y);
            acc1.z = fmaf(a, v1.z, acc1.z);
            acc1.w = fmaf(a, v1.w, acc1.w);
        }
    }
    ob[lane] = acc0;
    if (lane < 11) {
        ob[64 + lane] = acc1;
    } else if (lane < 14) {
        int mo = months[b];
        float enc = (float)(*encode_p);
        int base = (lane - 11) * 4;
        float4 oh;
        oh.x = (base + 0 == mo) ? enc : 0.f;
        oh.y = (base + 1 == mo) ? enc : 0.f;
        oh.z = (base + 2 == mo) ? enc : 0.f;
        oh.w = (base + 3 == mo) ? enc : 0.f;
        ob[64 + lane] = oh;
    }
}

// ---------------------------------------------------------------------------
extern "C" void kernel_launch(void* const* d_in, const int* in_sizes, int n_in,
                              void* d_out, int out_size, void* d_ws, size_t ws_size,
                              hipStream_t stream) {
    const float* topic_emb = (const float*)d_in[0];
    const int*   noun_ids  = (const int*)d_in[1];
    const int*   lengths   = (const int*)d_in[2];
    const int*   months    = (const int*)d_in[3];
    const int*   encode    = (const int*)d_in[4];
    const float* we        = (const float*)d_in[5];
    const float* k_w       = (const float*)d_in[6];
    // d_in[7] = k_b: cancels in softmax, never touches `value` -> unused.
    const float* q_w       = (const float*)d_in[8];
    const float* q_b       = (const float*)d_in[9];
    float* out = (float*)d_out;

    float* w_vec   = (float*)d_ws;       // 312 floats (padded to 512)
    float* s_vocab = w_vec + 512;        // 50000 floats (~202 KB total ws)

    compute_w_kernel<<<1, 320, 0, stream>>>(topic_emb, q_w, q_b, k_w, w_vec);
    vocab_score_kernel<<<(VOCAB + 3) / 4, 256, 0, stream>>>(we, w_vec, s_vocab);
    attn_kernel<<<NB / 4, 256, 0, stream>>>(noun_ids, lengths, months, encode,
                                            we, s_vocab, out);
}